// Round 4
// baseline (97.856 us; speedup 1.0000x reference)
//
#include <hip/hip_runtime.h>

#define TPB 256

typedef __attribute__((ext_vector_type(8))) short bf16x8;    // 8 bf16 = 4 VGPRs
typedef __attribute__((ext_vector_type(16))) float f32x16;   // 32x32 accumulator

__device__ inline unsigned short f2bf(float f) {             // RNE fp32->bf16
    unsigned u = __float_as_uint(f);
    return (unsigned short)((u + 0x7FFFu + ((u >> 16) & 1u)) >> 16);
}
__device__ inline float bf2f(unsigned short h) {
    return __uint_as_float((unsigned)h << 16);
}
__device__ inline uint4 pack8(unsigned short s0, unsigned short s1,
                              unsigned short s2, unsigned short s3,
                              unsigned short s4, unsigned short s5,
                              unsigned short s6, unsigned short s7) {
    uint4 v;
    v.x = (unsigned)s0 | ((unsigned)s1 << 16);
    v.y = (unsigned)s2 | ((unsigned)s3 << 16);
    v.z = (unsigned)s4 | ((unsigned)s5 << 16);
    v.w = (unsigned)s6 | ((unsigned)s7 << 16);
    return v;
}
__device__ inline bf16x8 as_frag(uint4 v) {
    union { uint4 u; bf16x8 f; } c; c.u = v; return c.f;
}

// Pack each point into MFMA K=16 operand rows (logical slot = half*8 + j,
// identical convention for A and B -> k-order agnostic; verified absmax=0).
//   A (source, a=-2p): [ahx ahy ahz  alx aly alz  ahx ahy ahz  1 1 1  alx aly alz  0]
//   B (target):        [thx thy thz  thx thy thz  tlx tly tlz  wh wm wl tlx tly tlz 0]
// sum_k A*B = (ah+al).(th+tl) + |t|^2 = -2 p.t + |t|^2   (|p|^2 added in epilogue, exact fp32)
__global__ __launch_bounds__(TPB) void prep_kernel(
        const float* __restrict__ a, const float* __restrict__ b,
        uint4* __restrict__ pAa, uint4* __restrict__ pBa,   // pred: A-fmt, B-fmt
        uint4* __restrict__ pAb, uint4* __restrict__ pBb,   // targ: A-fmt, B-fmt
        float* __restrict__ norms, unsigned* __restrict__ pmins,
        float* __restrict__ acc, unsigned* __restrict__ cnt, int n) {
    int idx = blockIdx.x * TPB + threadIdx.x;
    if (idx < 2 * n) {
        int isB = idx >= n;
        int i = isB ? idx - n : idx;
        const float* s = isB ? b : a;
        float x = s[3 * i], y = s[3 * i + 1], z = s[3 * i + 2];
        float w = x * x + y * y + z * z;
        norms[idx] = w;
        float ax = -2.0f * x, ay = -2.0f * y, az = -2.0f * z;
        unsigned short ahx = f2bf(ax), ahy = f2bf(ay), ahz = f2bf(az);
        unsigned short alx = f2bf(ax - bf2f(ahx));
        unsigned short aly = f2bf(ay - bf2f(ahy));
        unsigned short alz = f2bf(az - bf2f(ahz));
        unsigned short thx = f2bf(x), thy = f2bf(y), thz = f2bf(z);
        unsigned short tlx = f2bf(x - bf2f(thx));
        unsigned short tly = f2bf(y - bf2f(thy));
        unsigned short tlz = f2bf(z - bf2f(thz));
        unsigned short wh = f2bf(w);  float r1 = w - bf2f(wh);
        unsigned short wm = f2bf(r1); float r2 = r1 - bf2f(wm);
        unsigned short wl = f2bf(r2);
        const unsigned short ONE = 0x3F80;
        uint4* Ad = (isB ? pAb : pAa) + (size_t)i * 2;
        uint4* Bd = (isB ? pBb : pBa) + (size_t)i * 2;
        Ad[0] = pack8(ahx, ahy, ahz, alx, aly, alz, ahx, ahy);
        Ad[1] = pack8(ahz, ONE, ONE, ONE, alx, aly, alz, 0);
        Bd[0] = pack8(thx, thy, thz, thx, thy, thz, tlx, tly);
        Bd[1] = pack8(tlz, wh, wm, wl, tlx, tly, tlz, 0);
        pmins[idx] = 0xFFFFFFFFu;
    }
    if (idx == 0) { acc[0] = 0.0f; cnt[0] = 0u; }
}

// Barrier-free streaming minpass.  Round-3 post-mortem: the v_min fold was
// the VALU bottleneck (32 v_min per 32-target tile; plus AGPR read traffic
// when d-tiles overflowed the 128-reg cap).  This version processes a
// 64-row x 64-target pair-block per iteration: 4 MFMAs folded as
// rm = v_min3(rm, dX[i], dY[i]) -> 16 min3 per 2048 pairs (4x fewer fold
// ops/pair), with only TWO d-tiles live at a time (rm0-phase reuses regs
// for the rm1-phase) so everything stays in VGPRs under the 128 cap.
// B read global->reg (512 KB pack is L2-resident; LDS staging was the
// round-2 stall).  4-load rotating prefetch, name-rotated (no v_movs).
// Block = 4 waves x 64 rows = 256 rows; TS=8; grid = 2*64*8 = 1024 blocks
// = 4/CU, 16 waves/CU.
__global__ __launch_bounds__(TPB, 4) void minpass_kernel(
        const uint4* __restrict__ pAa, const uint4* __restrict__ pBa,
        const uint4* __restrict__ pAb, const uint4* __restrict__ pBb,
        const float* __restrict__ norms, unsigned* __restrict__ pmins, int n) {
    const int TS = 8;
    const int NRB = n / 256;          // 64 row-blocks (256 rows each)
    const int TGT = n / TS;           // 2048 targets per slice
    const int NIT = TGT / 64;         // 32 pair-block iterations

    int bid = blockIdx.x;
    int dir = bid / (NRB * TS);
    int rem = bid % (NRB * TS);
    int rbk = rem / TS;
    int ts  = rem % TS;

    const uint4* __restrict__ Ap = dir ? pAb : pAa;
    const uint4* __restrict__ Bp = dir ? pBa : pBb;

    const int tid = threadIdx.x;
    const int wid = tid >> 6, lane = tid & 63;
    const int lr = lane & 31, lh = lane >> 5;

    const int rowbase = rbk * 256 + wid * 64;
    bf16x8 a0 = as_frag(Ap[(size_t)(rowbase + lr) * 2 + lh]);
    bf16x8 a1 = as_frag(Ap[(size_t)(rowbase + 32 + lr) * 2 + lh]);

    float rm0[16], rm1[16];
#pragma unroll
    for (int i = 0; i < 16; ++i) { rm0[i] = __builtin_inff(); rm1[i] = __builtin_inff(); }
    f32x16 z = {};   // zero C operand

    // lane's B-frag pointer: 32-target tile tt lives at uint4-offset tt*64;
    // iteration j consumes tiles (2j, 2j+1).  Wave's lanes cover contiguous
    // 1KB segments (fully coalesced dwordx4).
    const uint4* __restrict__ bp = Bp + (size_t)(ts * TGT + lr) * 2 + lh;

    // two-phase pair-block: phase A folds rm0 (a0), phase B reuses the same
    // d registers for rm1 (a1).  16 v_min3 per phase.
#define PAIR_ITER(B0, B1) do {                                                  \
    bf16x8 b0 = as_frag(B0), b1 = as_frag(B1);                                  \
    f32x16 dX = __builtin_amdgcn_mfma_f32_32x32x16_bf16(a0, b0, z, 0, 0, 0);    \
    f32x16 dY = __builtin_amdgcn_mfma_f32_32x32x16_bf16(a0, b1, z, 0, 0, 0);    \
    _Pragma("unroll")                                                           \
    for (int i = 0; i < 16; ++i)                                                \
        rm0[i] = fminf(rm0[i], fminf(dX[i], dY[i]));   /* -> v_min3 */          \
    dX = __builtin_amdgcn_mfma_f32_32x32x16_bf16(a1, b0, z, 0, 0, 0);           \
    dY = __builtin_amdgcn_mfma_f32_32x32x16_bf16(a1, b1, z, 0, 0, 0);           \
    _Pragma("unroll")                                                           \
    for (int i = 0; i < 16; ++i)                                                \
        rm1[i] = fminf(rm1[i], fminf(dX[i], dY[i]));                            \
} while (0)

    // rotating 4-load prefetch, 2 iterations deep (load->use ~600 SIMD cyc)
    uint4 P0 = bp[0], P1 = bp[64], P2 = bp[128], P3 = bp[192];
    for (int j = 0; j + 4 <= NIT; j += 2) {
        PAIR_ITER(P0, P1);
        P0 = bp[(size_t)(2 * j + 4) * 64];
        P1 = bp[(size_t)(2 * j + 5) * 64];
        PAIR_ITER(P2, P3);
        P2 = bp[(size_t)(2 * j + 6) * 64];
        P3 = bp[(size_t)(2 * j + 7) * 64];
    }
    PAIR_ITER(P0, P1);   // iterations NIT-2, NIT-1
    PAIR_ITER(P2, P3);

    // fold over the 32 columns held by this lane-half (xor k<32 stays in half)
#pragma unroll
    for (int k = 1; k < 32; k <<= 1) {
#pragma unroll
        for (int i = 0; i < 16; ++i) {
            rm0[i] = fminf(rm0[i], __shfl_xor(rm0[i], k, 64));
            rm1[i] = fminf(rm1[i], __shfl_xor(rm1[i], k, 64));
        }
    }
    if (lr == 0) {   // lanes 0 and 32: rows (i&3)+8*(i>>2)+4*lh (+32 for a1)
        unsigned* pm = pmins + (size_t)dir * n;
        const float* nb = norms + (dir ? n : 0);
        int rb0 = rowbase + lh * 4;
#pragma unroll
        for (int i = 0; i < 16; ++i) {
            int r = (i & 3) + ((i >> 2) << 3);
            int r0 = rb0 + r, r1 = rb0 + 32 + r;
            // add |p|^2 exactly in fp32 after the min (monotone shift);
            // nonneg floats monotone under unsigned compare -> uint atomicMin
            atomicMin(&pm[r0], __float_as_uint(rm0[i] + nb[r0]));
            atomicMin(&pm[r1], __float_as_uint(rm1[i] + nb[r1]));
        }
    }
#undef PAIR_ITER
}

__global__ __launch_bounds__(TPB) void finalize_kernel(
        const uint4* __restrict__ pmins, float* __restrict__ acc,
        unsigned* __restrict__ cnt, float* __restrict__ out, int n, int nblocks) {
    int i = blockIdx.x * TPB + threadIdx.x;
    uint4 v = pmins[i];
    float sum = __uint_as_float(v.x) + __uint_as_float(v.y)
              + __uint_as_float(v.z) + __uint_as_float(v.w);
    for (int off = 32; off > 0; off >>= 1)
        sum += __shfl_down(sum, off, 64);
    __shared__ float wsum[TPB / 64];
    int lane = threadIdx.x & 63, wid = threadIdx.x >> 6;
    if (lane == 0) wsum[wid] = sum;
    __syncthreads();
    if (threadIdx.x == 0) {
        float t = 0.0f;
        for (int w = 0; w < TPB / 64; ++w) t += wsum[w];
        atomicAdd(acc, t);
        __threadfence();
        unsigned old = atomicAdd(cnt, 1u);
        if (old == (unsigned)(nblocks - 1)) {
            float a0 = atomicAdd(acc, 0.0f);
            out[0] = a0 / (float)(2 * n);
        }
    }
}

extern "C" void kernel_launch(void* const* d_in, const int* in_sizes, int n_in,
                              void* d_out, int out_size, void* d_ws, size_t ws_size,
                              hipStream_t stream) {
    const float* a = (const float*)d_in[0];
    const float* b = (const float*)d_in[1];
    int n = in_sizes[0] / 3;  // 16384
    float* out = (float*)d_out;
    char* ws = (char*)d_ws;
    float* acc = (float*)ws;                       // 1 float
    unsigned* cnt = (unsigned*)(ws + 8);           // 1 uint
    float* norms = (float*)(ws + 256);             // 2n f32 = 128 KB
    char* packs = ws + 256 + (size_t)2 * n * 4;
    size_t psz = (size_t)n * 32;                   // 512 KB per pack
    uint4* pAa = (uint4*)(packs);
    uint4* pBa = (uint4*)(packs + psz);
    uint4* pAb = (uint4*)(packs + 2 * psz);
    uint4* pBb = (uint4*)(packs + 3 * psz);
    unsigned* pmins = (unsigned*)(packs + 4 * psz);

    prep_kernel<<<(2 * n + TPB - 1) / TPB, TPB, 0, stream>>>(
        a, b, pAa, pBa, pAb, pBb, norms, pmins, acc, cnt, n);
    int mblocks = 2 * (n / 256) * 8;               // 1024
    minpass_kernel<<<mblocks, TPB, 0, stream>>>(
        pAa, pBa, pAb, pBb, norms, pmins, n);
    int fblocks = (2 * n / 4) / TPB;               // 32
    finalize_kernel<<<fblocks, TPB, 0, stream>>>(
        (const uint4*)pmins, acc, cnt, out, n, fblocks);
}

// Round 5
// 93.867 us; speedup vs baseline: 1.0425x; 1.0425x over previous
//
#include <hip/hip_runtime.h>

#define TPB 256

typedef __attribute__((ext_vector_type(8))) short bf16x8;    // 8 bf16 = 4 VGPRs
typedef __attribute__((ext_vector_type(16))) float f32x16;   // 32x32 accumulator

__device__ inline unsigned short f2bf(float f) {             // RNE fp32->bf16
    unsigned u = __float_as_uint(f);
    return (unsigned short)((u + 0x7FFFu + ((u >> 16) & 1u)) >> 16);
}
__device__ inline float bf2f(unsigned short h) {
    return __uint_as_float((unsigned)h << 16);
}
__device__ inline uint4 pack8(unsigned short s0, unsigned short s1,
                              unsigned short s2, unsigned short s3,
                              unsigned short s4, unsigned short s5,
                              unsigned short s6, unsigned short s7) {
    uint4 v;
    v.x = (unsigned)s0 | ((unsigned)s1 << 16);
    v.y = (unsigned)s2 | ((unsigned)s3 << 16);
    v.z = (unsigned)s4 | ((unsigned)s5 << 16);
    v.w = (unsigned)s6 | ((unsigned)s7 << 16);
    return v;
}
__device__ inline bf16x8 as_frag(uint4 v) {
    union { uint4 u; bf16x8 f; } c; c.u = v; return c.f;
}

// Pack each point into MFMA K=16 operand rows (logical slot = half*8 + j,
// identical convention for A and B -> k-order agnostic; verified absmax=0).
//   A (source, a=-2p): [ahx ahy ahz  alx aly alz  ahx ahy ahz  1 1 1  alx aly alz  0]
//   B (target):        [thx thy thz  thx thy thz  tlx tly tlz  wh wm wl tlx tly tlz 0]
// sum_k A*B = (ah+al).(th+tl) + |t|^2 = -2 p.t + |t|^2   (|p|^2 added in epilogue, exact fp32)
__global__ __launch_bounds__(TPB) void prep_kernel(
        const float* __restrict__ a, const float* __restrict__ b,
        uint4* __restrict__ pAa, uint4* __restrict__ pBa,   // pred: A-fmt, B-fmt
        uint4* __restrict__ pAb, uint4* __restrict__ pBb,   // targ: A-fmt, B-fmt
        float* __restrict__ norms, unsigned* __restrict__ pmins,
        float* __restrict__ acc, unsigned* __restrict__ cnt, int n) {
    int idx = blockIdx.x * TPB + threadIdx.x;
    if (idx < 2 * n) {
        int isB = idx >= n;
        int i = isB ? idx - n : idx;
        const float* s = isB ? b : a;
        float x = s[3 * i], y = s[3 * i + 1], z = s[3 * i + 2];
        float w = x * x + y * y + z * z;
        norms[idx] = w;
        float ax = -2.0f * x, ay = -2.0f * y, az = -2.0f * z;
        unsigned short ahx = f2bf(ax), ahy = f2bf(ay), ahz = f2bf(az);
        unsigned short alx = f2bf(ax - bf2f(ahx));
        unsigned short aly = f2bf(ay - bf2f(ahy));
        unsigned short alz = f2bf(az - bf2f(ahz));
        unsigned short thx = f2bf(x), thy = f2bf(y), thz = f2bf(z);
        unsigned short tlx = f2bf(x - bf2f(thx));
        unsigned short tly = f2bf(y - bf2f(thy));
        unsigned short tlz = f2bf(z - bf2f(thz));
        unsigned short wh = f2bf(w);  float r1 = w - bf2f(wh);
        unsigned short wm = f2bf(r1); float r2 = r1 - bf2f(wm);
        unsigned short wl = f2bf(r2);
        const unsigned short ONE = 0x3F80;
        uint4* Ad = (isB ? pAb : pAa) + (size_t)i * 2;
        uint4* Bd = (isB ? pBb : pBa) + (size_t)i * 2;
        Ad[0] = pack8(ahx, ahy, ahz, alx, aly, alz, ahx, ahy);
        Ad[1] = pack8(ahz, ONE, ONE, ONE, alx, aly, alz, 0);
        Bd[0] = pack8(thx, thy, thz, thx, thy, thz, tlx, tly);
        Bd[1] = pack8(tlz, wh, wm, wl, tlx, tly, tlz, 0);
        pmins[idx] = 0xFFFFFFFFu;
    }
    if (idx == 0) { acc[0] = 0.0f; cnt[0] = 0u; }
}

// Single-barrier LDS-staged minpass.  Round-4 post-mortem: fold-op count is
// NOT the limiter (min3 pairing with register reuse REGRESSED 32->45 us);
// the limiter is load latency + dependency serialization at ~2 waves/SIMD.
// This version:
//  - stages the block's full 1024-target slice (32 KB) into LDS ONCE with a
//    single __syncthreads (round-2's failure was 64 barriers + 32 vmcnt(0)
//    drains, not LDS itself); main loop streams ds_read_b128 (~120 cyc
//    latency vs 200-900 global), no barriers, no vmcnt drains.
//  - L2 read traffic drops 256 MB -> 64 MB (each slice fetched once/block).
//  - keeps round-3's proven fold dataflow: fresh d0/d1 per tile, plain fmin,
//    no cross-phase register reuse (no WAR serialization).
//  - small live set (~105 unified regs incl. z-in-AGPR) so (256,4)'s
//    4 waves/SIMD actually materializes.
// Block = 4 waves x 64 rows = 256 rows; TS=16 slices of 1024 targets;
// grid = 2*64*16 = 2048 blocks; LDS 33 KB -> 4 blocks/CU.
__global__ __launch_bounds__(TPB, 4) void minpass_kernel(
        const uint4* __restrict__ pAa, const uint4* __restrict__ pBa,
        const uint4* __restrict__ pAb, const uint4* __restrict__ pBb,
        const float* __restrict__ norms, unsigned* __restrict__ pmins, int n) {
    const int TS = 16;
    const int NRB = n / 256;          // 64 row-blocks (256 rows each)
    const int TGT = n / TS;           // 1024 targets per slice
    const int NT = TGT / 32;          // 32 B-tiles per wave

    int bid = blockIdx.x;
    int dir = bid / (NRB * TS);
    int rem = bid % (NRB * TS);
    int rbk = rem / TS;
    int ts  = rem % TS;

    const uint4* __restrict__ Ap = dir ? pAb : pAa;
    const uint4* __restrict__ Bp = dir ? pBa : pBb;

    __shared__ uint4 sbuf[2048 + 64];   // 1024 targets x 32B + 1-tile pad

    const int tid = threadIdx.x;
    const int wid = tid >> 6, lane = tid & 63;
    const int lr = lane & 31, lh = lane >> 5;

    // stage the slice: 8 fully-coalesced dwordx4 per thread, one barrier
    {
        const uint4* __restrict__ gs = Bp + (size_t)ts * TGT * 2;
#pragma unroll
        for (int i = 0; i < 8; ++i)
            sbuf[tid + i * TPB] = gs[tid + i * TPB];
    }

    const int rowbase = rbk * 256 + wid * 64;
    bf16x8 a0 = as_frag(Ap[(size_t)(rowbase + lr) * 2 + lh]);
    bf16x8 a1 = as_frag(Ap[(size_t)(rowbase + 32 + lr) * 2 + lh]);

    float rm0[16], rm1[16];
#pragma unroll
    for (int i = 0; i < 16; ++i) { rm0[i] = __builtin_inff(); rm1[i] = __builtin_inff(); }
    f32x16 z = {};   // zero C operand (AGPR residency is free: MFMA reads AGPRs natively)

    __syncthreads();   // the ONLY barrier

    // lane's LDS base: tile t at uint4-offset t*64; slot within tile lr*2+lh
    const uint4* __restrict__ sb = sbuf + ((lr << 1) | lh);

    bf16x8 b0 = as_frag(sb[0]);
    for (int t = 0; t < NT; t += 2) {
        bf16x8 b1 = as_frag(sb[(t + 1) * 64]);          // prefetch tile t+1
        {
            f32x16 d0 = __builtin_amdgcn_mfma_f32_32x32x16_bf16(a0, b0, z, 0, 0, 0);
            f32x16 d1 = __builtin_amdgcn_mfma_f32_32x32x16_bf16(a1, b0, z, 0, 0, 0);
#pragma unroll
            for (int i = 0; i < 16; ++i) {
                rm0[i] = fminf(rm0[i], d0[i]);
                rm1[i] = fminf(rm1[i], d1[i]);
            }
        }
        bf16x8 b2 = as_frag(sb[(t + 2) * 64]);          // prefetch tile t+2 (pad-safe)
        {
            f32x16 d0 = __builtin_amdgcn_mfma_f32_32x32x16_bf16(a0, b1, z, 0, 0, 0);
            f32x16 d1 = __builtin_amdgcn_mfma_f32_32x32x16_bf16(a1, b1, z, 0, 0, 0);
#pragma unroll
            for (int i = 0; i < 16; ++i) {
                rm0[i] = fminf(rm0[i], d0[i]);
                rm1[i] = fminf(rm1[i], d1[i]);
            }
        }
        b0 = b2;
    }

    // fold over the 32 columns held by this lane-half (xor k<32 stays in half)
#pragma unroll
    for (int k = 1; k < 32; k <<= 1) {
#pragma unroll
        for (int i = 0; i < 16; ++i) {
            rm0[i] = fminf(rm0[i], __shfl_xor(rm0[i], k, 64));
            rm1[i] = fminf(rm1[i], __shfl_xor(rm1[i], k, 64));
        }
    }
    if (lr == 0) {   // lanes 0 and 32: rows (i&3)+8*(i>>2)+4*lh (+32 for a1)
        unsigned* pm = pmins + (size_t)dir * n;
        const float* nb = norms + (dir ? n : 0);
        int rb0 = rowbase + lh * 4;
#pragma unroll
        for (int i = 0; i < 16; ++i) {
            int r = (i & 3) + ((i >> 2) << 3);
            int r0 = rb0 + r, r1 = rb0 + 32 + r;
            // add |p|^2 exactly in fp32 after the min (monotone shift);
            // nonneg floats monotone under unsigned compare -> uint atomicMin
            atomicMin(&pm[r0], __float_as_uint(rm0[i] + nb[r0]));
            atomicMin(&pm[r1], __float_as_uint(rm1[i] + nb[r1]));
        }
    }
}

__global__ __launch_bounds__(TPB) void finalize_kernel(
        const uint4* __restrict__ pmins, float* __restrict__ acc,
        unsigned* __restrict__ cnt, float* __restrict__ out, int n, int nblocks) {
    int i = blockIdx.x * TPB + threadIdx.x;
    uint4 v = pmins[i];
    float sum = __uint_as_float(v.x) + __uint_as_float(v.y)
              + __uint_as_float(v.z) + __uint_as_float(v.w);
    for (int off = 32; off > 0; off >>= 1)
        sum += __shfl_down(sum, off, 64);
    __shared__ float wsum[TPB / 64];
    int lane = threadIdx.x & 63, wid = threadIdx.x >> 6;
    if (lane == 0) wsum[wid] = sum;
    __syncthreads();
    if (threadIdx.x == 0) {
        float t = 0.0f;
        for (int w = 0; w < TPB / 64; ++w) t += wsum[w];
        atomicAdd(acc, t);
        __threadfence();
        unsigned old = atomicAdd(cnt, 1u);
        if (old == (unsigned)(nblocks - 1)) {
            float a0 = atomicAdd(acc, 0.0f);
            out[0] = a0 / (float)(2 * n);
        }
    }
}

extern "C" void kernel_launch(void* const* d_in, const int* in_sizes, int n_in,
                              void* d_out, int out_size, void* d_ws, size_t ws_size,
                              hipStream_t stream) {
    const float* a = (const float*)d_in[0];
    const float* b = (const float*)d_in[1];
    int n = in_sizes[0] / 3;  // 16384
    float* out = (float*)d_out;
    char* ws = (char*)d_ws;
    float* acc = (float*)ws;                       // 1 float
    unsigned* cnt = (unsigned*)(ws + 8);           // 1 uint
    float* norms = (float*)(ws + 256);             // 2n f32 = 128 KB
    char* packs = ws + 256 + (size_t)2 * n * 4;
    size_t psz = (size_t)n * 32;                   // 512 KB per pack
    uint4* pAa = (uint4*)(packs);
    uint4* pBa = (uint4*)(packs + psz);
    uint4* pAb = (uint4*)(packs + 2 * psz);
    uint4* pBb = (uint4*)(packs + 3 * psz);
    unsigned* pmins = (unsigned*)(packs + 4 * psz);

    prep_kernel<<<(2 * n + TPB - 1) / TPB, TPB, 0, stream>>>(
        a, b, pAa, pBa, pAb, pBb, norms, pmins, acc, cnt, n);
    int mblocks = 2 * (n / 256) * 16;              // 2048
    minpass_kernel<<<mblocks, TPB, 0, stream>>>(
        pAa, pBa, pAb, pBb, norms, pmins, n);
    int fblocks = (2 * n / 4) / TPB;               // 32
    finalize_kernel<<<fblocks, TPB, 0, stream>>>(
        (const uint4*)pmins, acc, cnt, out, n, fblocks);
}

// Round 7
// 84.579 us; speedup vs baseline: 1.1570x; 1.1098x over previous
//
#include <hip/hip_runtime.h>

#define TPB 256

typedef __attribute__((ext_vector_type(8))) short bf16x8;    // 8 bf16 = 4 VGPRs
typedef __attribute__((ext_vector_type(16))) float f32x16;   // 32x32 accumulator

__device__ inline unsigned short f2bf(float f) {             // RNE fp32->bf16
    unsigned u = __float_as_uint(f);
    return (unsigned short)((u + 0x7FFFu + ((u >> 16) & 1u)) >> 16);
}
__device__ inline float bf2f(unsigned short h) {
    return __uint_as_float((unsigned)h << 16);
}
__device__ inline uint4 pack8(unsigned short s0, unsigned short s1,
                              unsigned short s2, unsigned short s3,
                              unsigned short s4, unsigned short s5,
                              unsigned short s6, unsigned short s7) {
    uint4 v;
    v.x = (unsigned)s0 | ((unsigned)s1 << 16);
    v.y = (unsigned)s2 | ((unsigned)s3 << 16);
    v.z = (unsigned)s4 | ((unsigned)s5 << 16);
    v.w = (unsigned)s6 | ((unsigned)s7 << 16);
    return v;
}
__device__ inline bf16x8 as_frag(uint4 v) {
    union { uint4 u; bf16x8 f; } c; c.u = v; return c.f;
}

// Pack each point into MFMA K=16 operand rows (logical slot = half*8 + j,
// identical convention for A and B -> k-order agnostic; verified absmax=0).
//   A (source, a=-2p): [ahx ahy ahz  alx aly alz  ahx ahy ahz  1 1 1  alx aly alz  0]
//   B (target):        [thx thy thz  thx thy thz  tlx tly tlz  wh wm wl tlx tly tlz 0]
// sum_k A*B = (ah+al).(th+tl) + |t|^2 = -2 p.t + |t|^2   (|p|^2 added in epilogue, exact fp32)
__global__ __launch_bounds__(TPB) void prep_kernel(
        const float* __restrict__ a, const float* __restrict__ b,
        uint4* __restrict__ pAa, uint4* __restrict__ pBa,   // pred: A-fmt, B-fmt
        uint4* __restrict__ pAb, uint4* __restrict__ pBb,   // targ: A-fmt, B-fmt
        float* __restrict__ norms, unsigned* __restrict__ pmins,
        float* __restrict__ acc, unsigned* __restrict__ cnt, int n) {
    int idx = blockIdx.x * TPB + threadIdx.x;
    if (idx < 2 * n) {
        int isB = idx >= n;
        int i = isB ? idx - n : idx;
        const float* s = isB ? b : a;
        float x = s[3 * i], y = s[3 * i + 1], z = s[3 * i + 2];
        float w = x * x + y * y + z * z;
        norms[idx] = w;
        float ax = -2.0f * x, ay = -2.0f * y, az = -2.0f * z;
        unsigned short ahx = f2bf(ax), ahy = f2bf(ay), ahz = f2bf(az);
        unsigned short alx = f2bf(ax - bf2f(ahx));
        unsigned short aly = f2bf(ay - bf2f(ahy));
        unsigned short alz = f2bf(az - bf2f(ahz));
        unsigned short thx = f2bf(x), thy = f2bf(y), thz = f2bf(z);
        unsigned short tlx = f2bf(x - bf2f(thx));
        unsigned short tly = f2bf(y - bf2f(thy));
        unsigned short tlz = f2bf(z - bf2f(thz));
        unsigned short wh = f2bf(w);  float r1 = w - bf2f(wh);
        unsigned short wm = f2bf(r1); float r2 = r1 - bf2f(wm);
        unsigned short wl = f2bf(r2);
        const unsigned short ONE = 0x3F80;
        uint4* Ad = (isB ? pAb : pAa) + (size_t)i * 2;
        uint4* Bd = (isB ? pBb : pBa) + (size_t)i * 2;
        Ad[0] = pack8(ahx, ahy, ahz, alx, aly, alz, ahx, ahy);
        Ad[1] = pack8(ahz, ONE, ONE, ONE, alx, aly, alz, 0);
        Bd[0] = pack8(thx, thy, thz, thx, thy, thz, tlx, tly);
        Bd[1] = pack8(tlz, wh, wm, wl, tlx, tly, tlz, 0);
        pmins[idx] = 0xFFFFFFFFu;
    }
    if (idx == 0) { acc[0] = 0.0f; cnt[0] = 0u; }
}

// Barrier-free streaming minpass = round-3's structure (the measured winner,
// absmax=0) with the register-allocation fix.
//
// Cross-round diagnosis (R1-R5): __launch_bounds__(256,4)'s 128-reg budget
// made the allocator split 64 arch VGPR + 64 AGPR and shuttle every fold
// operand through v_accvgpr_read/write (R4: 63k VALU-cyc/SIMD vs ~10k
// algorithmic = 6x inflation, ~200 extra instrs/iter = z-copies + d-tile
// reads + rm ping-pong), while delivering only 2 waves/SIMD anyway.
// R6's inline-asm v_min3 fix FAILED correctness: LLVM does not insert the
// MFMA->inline-asm-VALU-read wait states (stale d reads) -- do not touch
// MFMA results with asm without manual s_nop padding.
//
// Fix here: __launch_bounds__(256, 2) -> 256-reg budget.  The ~120-reg live
// set fits entirely in arch VGPRs: no accvgpr traffic, no z-copies, clean
// v_min folds.  Grid 512 = exactly 2 blocks/CU, balanced co-residency.
// Block = 4 waves x 64 rows = 256 rows; TS=4 (4096 targets/wave);
// B read global->reg (512 KB pack is L2-resident; both LDS variants were
// measured slower).  4-tile rotating prefetch, ~300 cyc load->use distance.
__global__ __launch_bounds__(TPB, 2) void minpass_kernel(
        const uint4* __restrict__ pAa, const uint4* __restrict__ pBa,
        const uint4* __restrict__ pAb, const uint4* __restrict__ pBb,
        const float* __restrict__ norms, unsigned* __restrict__ pmins, int n) {
    const int TS = 4;
    const int NRB = n / 256;          // 64 row-blocks (256 rows each)
    const int TGT = n / TS;           // 4096 targets per slice
    const int NT = TGT / 32;          // 128 B-tiles per wave

    int bid = blockIdx.x;
    int dir = bid / (NRB * TS);
    int rem = bid % (NRB * TS);
    int rbk = rem / TS;
    int ts  = rem % TS;

    const uint4* __restrict__ Ap = dir ? pAb : pAa;
    const uint4* __restrict__ Bp = dir ? pBa : pBb;

    const int tid = threadIdx.x;
    const int wid = tid >> 6, lane = tid & 63;
    const int lr = lane & 31, lh = lane >> 5;

    const int rowbase = rbk * 256 + wid * 64;
    bf16x8 a0 = as_frag(Ap[(size_t)(rowbase + lr) * 2 + lh]);
    bf16x8 a1 = as_frag(Ap[(size_t)(rowbase + 32 + lr) * 2 + lh]);

    float rm0[16], rm1[16];
#pragma unroll
    for (int i = 0; i < 16; ++i) { rm0[i] = __builtin_inff(); rm1[i] = __builtin_inff(); }
    f32x16 z = {};   // zero C operand

    // lane's B-frag pointer: 32-target tile t lives at uint4-offset t*64.
    // Wave's 64 lanes cover a contiguous 1KB segment (fully coalesced dwordx4).
    const uint4* __restrict__ bp = Bp + (size_t)(ts * TGT + lr) * 2 + lh;

#define COMPUTE_TILE(X) do {                                                   \
    bf16x8 bb = as_frag(X);                                                    \
    f32x16 d0 = __builtin_amdgcn_mfma_f32_32x32x16_bf16(a0, bb, z, 0, 0, 0);   \
    f32x16 d1 = __builtin_amdgcn_mfma_f32_32x32x16_bf16(a1, bb, z, 0, 0, 0);   \
    _Pragma("unroll")                                                          \
    for (int i = 0; i < 16; ++i) {                                             \
        rm0[i] = fminf(rm0[i], d0[i]);                                         \
        rm1[i] = fminf(rm1[i], d1[i]);                                         \
    }                                                                          \
} while (0)

    // rotating 4-tile prefetch: each load has ~3 tile-computes before use
    uint4 A0 = bp[0], A1 = bp[64], A2 = bp[128], A3 = bp[192];
    for (int t = 0; t + 4 < NT; t += 4) {
        COMPUTE_TILE(A0); A0 = bp[(t + 4) * 64];
        COMPUTE_TILE(A1); A1 = bp[(t + 5) * 64];
        COMPUTE_TILE(A2); A2 = bp[(t + 6) * 64];
        COMPUTE_TILE(A3); A3 = bp[(t + 7) * 64];
    }
    COMPUTE_TILE(A0); COMPUTE_TILE(A1); COMPUTE_TILE(A2); COMPUTE_TILE(A3);
#undef COMPUTE_TILE

    // fold over the 32 columns held by this lane-half (xor k<32 stays in half)
#pragma unroll
    for (int k = 1; k < 32; k <<= 1) {
#pragma unroll
        for (int i = 0; i < 16; ++i) {
            rm0[i] = fminf(rm0[i], __shfl_xor(rm0[i], k, 64));
            rm1[i] = fminf(rm1[i], __shfl_xor(rm1[i], k, 64));
        }
    }
    if (lr == 0) {   // lanes 0 and 32: rows (i&3)+8*(i>>2)+4*lh (+32 for a1)
        unsigned* pm = pmins + (size_t)dir * n;
        const float* nb = norms + (dir ? n : 0);
        int rb0 = rowbase + lh * 4;
#pragma unroll
        for (int i = 0; i < 16; ++i) {
            int r = (i & 3) + ((i >> 2) << 3);
            int r0 = rb0 + r, r1 = rb0 + 32 + r;
            // add |p|^2 exactly in fp32 after the min (monotone shift);
            // nonneg floats monotone under unsigned compare -> uint atomicMin
            atomicMin(&pm[r0], __float_as_uint(rm0[i] + nb[r0]));
            atomicMin(&pm[r1], __float_as_uint(rm1[i] + nb[r1]));
        }
    }
}

__global__ __launch_bounds__(TPB) void finalize_kernel(
        const uint4* __restrict__ pmins, float* __restrict__ acc,
        unsigned* __restrict__ cnt, float* __restrict__ out, int n, int nblocks) {
    int i = blockIdx.x * TPB + threadIdx.x;
    uint4 v = pmins[i];
    float sum = __uint_as_float(v.x) + __uint_as_float(v.y)
              + __uint_as_float(v.z) + __uint_as_float(v.w);
    for (int off = 32; off > 0; off >>= 1)
        sum += __shfl_down(sum, off, 64);
    __shared__ float wsum[TPB / 64];
    int lane = threadIdx.x & 63, wid = threadIdx.x >> 6;
    if (lane == 0) wsum[wid] = sum;
    __syncthreads();
    if (threadIdx.x == 0) {
        float t = 0.0f;
        for (int w = 0; w < TPB / 64; ++w) t += wsum[w];
        atomicAdd(acc, t);
        __threadfence();
        unsigned old = atomicAdd(cnt, 1u);
        if (old == (unsigned)(nblocks - 1)) {
            float a0 = atomicAdd(acc, 0.0f);
            out[0] = a0 / (float)(2 * n);
        }
    }
}

extern "C" void kernel_launch(void* const* d_in, const int* in_sizes, int n_in,
                              void* d_out, int out_size, void* d_ws, size_t ws_size,
                              hipStream_t stream) {
    const float* a = (const float*)d_in[0];
    const float* b = (const float*)d_in[1];
    int n = in_sizes[0] / 3;  // 16384
    float* out = (float*)d_out;
    char* ws = (char*)d_ws;
    float* acc = (float*)ws;                       // 1 float
    unsigned* cnt = (unsigned*)(ws + 8);           // 1 uint
    float* norms = (float*)(ws + 256);             // 2n f32 = 128 KB
    char* packs = ws + 256 + (size_t)2 * n * 4;
    size_t psz = (size_t)n * 32;                   // 512 KB per pack
    uint4* pAa = (uint4*)(packs);
    uint4* pBa = (uint4*)(packs + psz);
    uint4* pAb = (uint4*)(packs + 2 * psz);
    uint4* pBb = (uint4*)(packs + 3 * psz);
    unsigned* pmins = (unsigned*)(packs + 4 * psz);

    prep_kernel<<<(2 * n + TPB - 1) / TPB, TPB, 0, stream>>>(
        a, b, pAa, pBa, pAb, pBb, norms, pmins, acc, cnt, n);
    int mblocks = 2 * (n / 256) * 4;               // 512 = 2 blocks/CU exactly
    minpass_kernel<<<mblocks, TPB, 0, stream>>>(
        pAa, pBa, pAb, pBb, norms, pmins, n);
    int fblocks = (2 * n / 4) / TPB;               // 32
    finalize_kernel<<<fblocks, TPB, 0, stream>>>(
        (const uint4*)pmins, acc, cnt, out, n, fblocks);
}